// Round 3
// baseline (623.248 us; speedup 1.0000x reference)
//
#include <hip/hip_runtime.h>
#include <hip/hip_bf16.h>

// ---------------------------------------------------------------------------
// ImageTransformerDenoiser block on MI355X (gfx950).
// B=4, H=W=128, D_MODEL=256, N_HEADS=4, D_HEAD=64, COND=256, D_FF=512, WS=8, SHIFT=4
// Pipeline: wconv -> scales -> rmsnorm1 -> qkv GEMM -> qknorm+rope+window ->
//           window attention -> outproj GEMM(+resid) -> rmsnorm2 ->
//           fused up GEMM + gelu gate -> down GEMM(+resid) -> d_out (fp32)
// ---------------------------------------------------------------------------

using short8 = __attribute__((ext_vector_type(8))) short;
using f32x4  = __attribute__((ext_vector_type(4))) float;

#define DEVINL __device__ __forceinline__

DEVINL float bf2f(unsigned short u) {
    union { unsigned u; float f; } v; v.u = ((unsigned)u) << 16; return v.f;
}
DEVINL unsigned short f2bf(float f) { // round-to-nearest-even
    union { float f; unsigned u; } v; v.f = f;
    unsigned u = v.u;
    return (unsigned short)((u + 0x7FFFu + ((u >> 16) & 1u)) >> 16);
}
DEVINL void unpack8(uint4 pk, float* f) {
    unsigned w[4] = { pk.x, pk.y, pk.z, pk.w };
#pragma unroll
    for (int t = 0; t < 4; ++t) {
        union { unsigned u; float f; } lo, hi;
        lo.u = w[t] << 16; hi.u = w[t] & 0xffff0000u;
        f[2 * t] = lo.f; f[2 * t + 1] = hi.f;
    }
}
// async global->LDS, 16B per lane; LDS dest must be wave-uniform base (HW adds lane*16)
DEVINL void gload_lds16(const void* g, void* l) {
    __builtin_amdgcn_global_load_lds(
        (__attribute__((address_space(1))) void*)(unsigned long long)(uintptr_t)g,
        (__attribute__((address_space(3))) void*)(unsigned)(uintptr_t)l,
        16, 0, 0);
}

// ---------------------------------------------------------------------------
// 1) convert all four weight matrices to bf16 into ws
//    layout (elements): qkv[0,196608) out[196608,262144) up[262144,524288) down[524288,655360)
__global__ __launch_bounds__(256)
void wconv_kernel(const float* __restrict__ qkvw, const float* __restrict__ outw,
                  const float* __restrict__ upw, const float* __restrict__ downw,
                  unsigned short* __restrict__ dst)
{
    const int i = blockIdx.x * 256 + threadIdx.x; // grid exactly 655360/256
    float v;
    if (i < 196608)      v = qkvw[i];
    else if (i < 262144) v = outw[i - 196608];
    else if (i < 524288) v = upw[i - 262144];
    else                 v = downw[i - 524288];
    dst[i] = f2bf(v);
}

// ---------------------------------------------------------------------------
// 2) s{1,2}[b][c] = dot(cond[b], norm_w[c]) + 1
__global__ __launch_bounds__(256)
void scales_kernel(const float* __restrict__ cond, const float* __restrict__ n1w,
                   const float* __restrict__ n2w, float* __restrict__ s1, float* __restrict__ s2)
{
    const int b = blockIdx.x & 3, which = blockIdx.x >> 2;
    const int c = threadIdx.x;
    const float* wrow = (which ? n2w : n1w) + (size_t)c * 256;
    const float* cb = cond + (size_t)b * 256;
    float acc = 0.f;
    for (int j = 0; j < 256; ++j) acc += cb[j] * wrow[j];
    (which ? s2 : s1)[b * 256 + c] = acc + 1.0f;
}

// ---------------------------------------------------------------------------
// 3) RMSNorm: one wave per token (256 ch), out bf16
__global__ __launch_bounds__(256)
void rmsnorm_kernel(const float* __restrict__ x, const float* __restrict__ s,
                    unsigned short* __restrict__ out)
{
    const int t = blockIdx.x * 4 + (threadIdx.x >> 6);
    const int lane = threadIdx.x & 63;
    const float4 xv = *(const float4*)(x + (size_t)t * 256 + lane * 4);
    float ss = xv.x * xv.x + xv.y * xv.y + xv.z * xv.z + xv.w * xv.w;
#pragma unroll
    for (int off = 32; off; off >>= 1) ss += __shfl_xor(ss, off);
    const float rstd = rsqrtf(ss * (1.f / 256.f) + 1e-6f);
    const int b = t >> 14; // 16384 tokens per batch image
    const float4 sv = *(const float4*)(s + b * 256 + lane * 4);
    unsigned short o[4] = { f2bf(xv.x * sv.x * rstd), f2bf(xv.y * sv.y * rstd),
                            f2bf(xv.z * sv.z * rstd), f2bf(xv.w * sv.w * rstd) };
    *(uint2*)(out + (size_t)t * 256 + lane * 4) = *(uint2*)o;
}

// ---------------------------------------------------------------------------
// 4) GEMM  C[M,N] = A[M,K] @ Bw[N,K]^T   (bf16 in, fp32 acc)
//    m97 structure: 128x128 tile, BK=64, 4 waves (2x2 of 64x64), 16x16x32 MFMA,
//    global_load_lds dwordx4 staging, linear LDS (T2 swizzle is null on 2-phase).
//    EPI 0: bf16 out | 1: fp32 out = resid + acc | 2: up+gate: Bw rows n and 512+n,
//           out bf16 = acc_a * gelu_exact(acc_g), N must be 512.
template<int EPI>
__global__ __launch_bounds__(256)
void gemm_bt(const unsigned short* __restrict__ A, const unsigned short* __restrict__ Bw,
             const float* __restrict__ resid, void* __restrict__ outp,
             int M, int N, int K)
{
    __shared__ char smem[(EPI == 2) ? 49152 : 32768];
    const int tid = threadIdx.x;
    const int wave = tid >> 6, lane = tid & 63;
    const int n0 = blockIdx.x * 128;
    const int m0 = blockIdx.y * 128;
    const int wm = wave >> 1, wn = wave & 1;

    f32x4 acc[4][4] = {};
    f32x4 accg[4][4] = {};

    const int lrow8 = lane >> 3;        // 0..7
    const int skel = (lane & 7) * 8;    // k element within BK

    for (int k0 = 0; k0 < K; k0 += 64) {
        __syncthreads();
#pragma unroll
        for (int i = 0; i < 4; ++i) {
            const int chunk = wave * 4 + i;       // 16 chunks of 1024B = 8 rows each
            const int row = chunk * 8 + lrow8;
            const unsigned short* ga = A  + (size_t)(m0 + row) * K + k0 + skel;
            const unsigned short* gb = Bw + (size_t)(n0 + row) * K + k0 + skel;
            gload_lds16(ga, smem + chunk * 1024);
            gload_lds16(gb, smem + 16384 + chunk * 1024);
            if constexpr (EPI == 2) {
                const unsigned short* gg = Bw + (size_t)(512 + n0 + row) * K + k0 + skel;
                gload_lds16(gg, smem + 32768 + chunk * 1024);
            }
        }
        __syncthreads();
#pragma unroll
        for (int kk = 0; kk < 2; ++kk) {
            const int kb = kk * 64 + (lane >> 4) * 16; // byte offset in 128B row
            short8 a[4], b[4], bg[4];
#pragma unroll
            for (int m = 0; m < 4; ++m)
                a[m] = *(const short8*)(smem + (wm * 64 + m * 16 + (lane & 15)) * 128 + kb);
#pragma unroll
            for (int n = 0; n < 4; ++n) {
                b[n] = *(const short8*)(smem + 16384 + (wn * 64 + n * 16 + (lane & 15)) * 128 + kb);
                if constexpr (EPI == 2)
                    bg[n] = *(const short8*)(smem + 32768 + (wn * 64 + n * 16 + (lane & 15)) * 128 + kb);
            }
#pragma unroll
            for (int m = 0; m < 4; ++m)
#pragma unroll
                for (int n = 0; n < 4; ++n) {
                    acc[m][n] = __builtin_amdgcn_mfma_f32_16x16x32_bf16(a[m], b[n], acc[m][n], 0, 0, 0);
                    if constexpr (EPI == 2)
                        accg[m][n] = __builtin_amdgcn_mfma_f32_16x16x32_bf16(a[m], bg[n], accg[m][n], 0, 0, 0);
                }
        }
    }
    // epilogue: C row = (lane>>4)*4 + j, col = lane&15 (m89-verified layout)
    const int rb = m0 + wm * 64 + ((lane >> 4) << 2);
    const int cb = n0 + wn * 64 + (lane & 15);
#pragma unroll
    for (int m = 0; m < 4; ++m)
#pragma unroll
        for (int n = 0; n < 4; ++n)
#pragma unroll
            for (int j = 0; j < 4; ++j) {
                const int row = rb + m * 16 + j;
                const int col = cb + n * 16;
                const size_t idx = (size_t)row * N + col;
                if constexpr (EPI == 0)
                    ((unsigned short*)outp)[idx] = f2bf(acc[m][n][j]);
                if constexpr (EPI == 1)
                    ((float*)outp)[idx] = resid[idx] + acc[m][n][j];
                if constexpr (EPI == 2) {
                    const float g = accg[m][n][j];
                    const float h = acc[m][n][j] * (0.5f * g * (1.0f + erff(g * 0.70710678118654752f)));
                    ((unsigned short*)outp)[idx] = f2bf(h);
                }
            }
}

// ---------------------------------------------------------------------------
// 5) q/k L2-norm (*sqrt(10)) + RoPE + shifted-window scatter. One wave per (token, head).
__global__ __launch_bounds__(256)
void windowrope_kernel(const unsigned short* __restrict__ qkv, const float* __restrict__ pos,
                       const float* __restrict__ freqs, const float* __restrict__ sattn,
                       unsigned short* __restrict__ qw, unsigned short* __restrict__ kw,
                       unsigned short* __restrict__ vw)
{
    const int gid = blockIdx.x * 4 + (threadIdx.x >> 6);
    const int lane = threadIdx.x & 63;      // d
    const int t = gid >> 2, n = gid & 3;
    const int b = t >> 14;
    const int h = (t >> 7) & 127, w = t & 127;

    const size_t base = (size_t)t * 768 + n * 64 + lane;
    float q = bf2f(qkv[base]);
    float k = bf2f(qkv[base + 256]);
    const float v = bf2f(qkv[base + 512]);

    float sq = q * q, sk = k * k;
#pragma unroll
    for (int off = 32; off; off >>= 1) { sq += __shfl_xor(sq, off); sk += __shfl_xor(sk, off); }
    const float sc = sqrtf(sattn[n]);
    q *= sc * rsqrtf(sq + 1e-6f);   // sum (not mean) + eps, per reference
    k *= sc * rsqrtf(sk + 1e-6f);

    const float qo = __shfl_xor(q, 16);   // rope partner (d ^ 16), all lanes execute
    const float ko = __shfl_xor(k, 16);
    if (lane < 32) {
        const int i = lane & 15;
        const float p = pos[(size_t)t * 2 + (i >> 3)];   // theta[0:8]=pos_h, [8:16]=pos_w
        const float th = p * freqs[n * 8 + (i & 7)];
        float sth, cth;
        sincosf(th, &sth, &cth);
        if (lane < 16) { q = q * cth - qo * sth; k = k * cth - ko * sth; }
        else           { q = q * cth + qo * sth; k = k * cth + ko * sth; }
    }

    // roll(+4,+4): token (h,w) lands at rolled coords (h+4, w+4) mod 128
    const int hr = (h + 4) & 127, wr = (w + 4) & 127;
    const int wh = hr >> 3, ww = wr >> 3;
    const int qp = (hr & 7) * 8 + (wr & 7);
    const size_t wbase = ((size_t)((b * 4 + n) * 256 + wh * 16 + ww) * 64 + qp) * 64 + lane;
    qw[wbase] = f2bf(q);
    kw[wbase] = f2bf(k);
    vw[wbase] = f2bf(v);
}

// ---------------------------------------------------------------------------
// 6) per-window attention. 1 wave per window (64 queries, lane = query row).
//    ||q||=||k||=sqrt(10) => scores in [-10,10]: fixed-max softmax (no max pass).
__global__ __launch_bounds__(64, 1)
void attn_kernel(const unsigned short* __restrict__ qw, const unsigned short* __restrict__ kw,
                 const unsigned short* __restrict__ vw, unsigned short* __restrict__ otok)
{
    __shared__ unsigned short Ks[4096];
    __shared__ unsigned short Vs[4096];
    const int bid = blockIdx.x;                  // ((b*4+n)*16+wh)*16+ww
    const int lane = threadIdx.x;
    const size_t wbase = (size_t)bid * 4096;

#pragma unroll
    for (int i = 0; i < 8; ++i) {
        const int idx = (i * 64 + lane) * 8;
        *(uint4*)(Ks + idx) = *(const uint4*)(kw + wbase + idx);
        *(uint4*)(Vs + idx) = *(const uint4*)(vw + wbase + idx);
    }
    float q[64];
#pragma unroll
    for (int i = 0; i < 8; ++i) {
        const uint4 pk = *(const uint4*)(qw + wbase + (size_t)lane * 64 + i * 8);
        unpack8(pk, q + i * 8);
    }
    __syncthreads();

    const int wh = (bid >> 4) & 15, ww = bid & 15;
    // mask factorization: (is_top => qa==ka) && (is_left => ql==kl); bit j = key allowed
    unsigned long long mask = ~0ull;
    if (wh == 0) mask &= (lane < 32) ? 0x00000000FFFFFFFFull : 0xFFFFFFFF00000000ull;
    if (ww == 0) mask &= ((lane & 7) < 4) ? 0x0F0F0F0F0F0F0F0Full : 0xF0F0F0F0F0F0F0F0ull;

    float o[64];
#pragma unroll
    for (int d = 0; d < 64; ++d) o[d] = 0.f;
    float sum = 0.f;

    for (int j = 0; j < 64; ++j) {
        float part[8];
#pragma unroll
        for (int dv = 0; dv < 8; ++dv) {
            const uint4 pk = *(const uint4*)(Ks + j * 64 + dv * 8);
            float f[8]; unpack8(pk, f);
            float a = 0.f;
#pragma unroll
            for (int u = 0; u < 8; ++u) a = fmaf(q[dv * 8 + u], f[u], a);
            part[dv] = a;
        }
        float s = ((part[0] + part[1]) + (part[2] + part[3])) +
                  ((part[4] + part[5]) + (part[6] + part[7]));
        float p = ((mask >> j) & 1ull) ? __expf(s - 10.f) : 0.f;
        sum += p;
#pragma unroll
        for (int dv = 0; dv < 8; ++dv) {
            const uint4 pk = *(const uint4*)(Vs + j * 64 + dv * 8);
            float f[8]; unpack8(pk, f);
#pragma unroll
            for (int u = 0; u < 8; ++u) o[dv * 8 + u] = fmaf(p, f[u], o[dv * 8 + u]);
        }
    }
    const float inv = 1.f / sum;

    // un-window + roll(-4,-4): query (wh*8+qh, ww*8+qw) -> token ((..)-4 mod 128)
    const int b = bid >> 10, n = (bid >> 8) & 3;
    const int h = (wh * 8 + (lane >> 3) - 4) & 127;
    const int w = (ww * 8 + (lane & 7) - 4) & 127;
    unsigned short* dst = otok + ((size_t)(b * 128 + h) * 128 + w) * 256 + n * 64;
#pragma unroll
    for (int i = 0; i < 8; ++i) {
        unsigned short tmp[8];
#pragma unroll
        for (int u = 0; u < 8; ++u) tmp[u] = f2bf(o[i * 8 + u] * inv);
        *(uint4*)(dst + i * 8) = *(uint4*)tmp;
    }
}

// ---------------------------------------------------------------------------
extern "C" void kernel_launch(void* const* d_in, const int* in_sizes, int n_in,
                              void* d_out, int out_size, void* d_ws, size_t ws_size,
                              hipStream_t stream)
{
    (void)in_sizes; (void)n_in; (void)out_size; (void)ws_size;
    const float* x     = (const float*)d_in[0];
    const float* pos   = (const float*)d_in[1];
    const float* cond  = (const float*)d_in[2];
    const float* n1w   = (const float*)d_in[3];
    const float* qkvw  = (const float*)d_in[4];
    const float* sattn = (const float*)d_in[5];
    const float* freqs = (const float*)d_in[6];
    const float* outw  = (const float*)d_in[7];
    const float* n2w   = (const float*)d_in[8];
    const float* upw   = (const float*)d_in[9];
    const float* downw = (const float*)d_in[10];

    // workspace layout (bytes), regions time-aliased; peak need ~203.5 MB
    char* ws = (char*)d_ws;
    unsigned short* WB    = (unsigned short*)(ws);            // bf16 weights, 655360 elems
    unsigned short* Wqkv  = WB;
    unsigned short* Wout  = WB + 196608;
    unsigned short* Wup   = WB + 262144;
    unsigned short* Wdown = WB + 524288;
    float* S1 = (float*)(ws + 1310720);
    float* S2 = (float*)(ws + 1314816);
    unsigned short* XN   = (unsigned short*)(ws + 2097152);   // 33.5MB  (t1-t2)
    unsigned short* QW   = (unsigned short*)(ws + 2097152);   // t3-t4 (XN dead)
    unsigned short* KW   = (unsigned short*)(ws + 35651584);
    unsigned short* VW   = (unsigned short*)(ws + 69206016);
    unsigned short* QKV  = (unsigned short*)(ws + 102760448); // 100.7MB (t2-t3)
    unsigned short* OTOK = (unsigned short*)(ws + 102760448); // t4-t5 (QKV dead)
    float*          X1   = (float*)(ws + 136314880);          // 67MB (t5-end, QKV dead)
    unsigned short* XN2  = (unsigned short*)(ws + 2097152);   // t6-t7 (QW dead)
    unsigned short* HG   = (unsigned short*)(ws + 35651584);  // 67MB t7-t9 (KW/VW dead)

    wconv_kernel<<<2560, 256, 0, stream>>>(qkvw, outw, upw, downw, WB);
    scales_kernel<<<8, 256, 0, stream>>>(cond, n1w, n2w, S1, S2);
    rmsnorm_kernel<<<16384, 256, 0, stream>>>(x, S1, XN);
    gemm_bt<0><<<dim3(6, 512), 256, 0, stream>>>(XN, Wqkv, nullptr, QKV, 65536, 768, 256);
    windowrope_kernel<<<65536, 256, 0, stream>>>(QKV, pos, freqs, sattn, QW, KW, VW);
    attn_kernel<<<4096, 64, 0, stream>>>(QW, KW, VW, OTOK);
    gemm_bt<1><<<dim3(2, 512), 256, 0, stream>>>(OTOK, Wout, x, X1, 65536, 256, 256);
    rmsnorm_kernel<<<16384, 256, 0, stream>>>(X1, S2, XN2);
    gemm_bt<2><<<dim3(4, 512), 256, 0, stream>>>(XN2, Wup, nullptr, HG, 65536, 512, 256);
    gemm_bt<1><<<dim3(2, 512), 256, 0, stream>>>(HG, Wdown, X1, (float*)d_out, 65536, 256, 512);
}

// Round 6
// 564.931 us; speedup vs baseline: 1.1032x; 1.1032x over previous
//
#include <hip/hip_runtime.h>
#include <hip/hip_bf16.h>

// ---------------------------------------------------------------------------
// ImageTransformerDenoiser block on MI355X (gfx950).
// B=4, H=W=128, D_MODEL=256, N_HEADS=4, D_HEAD=64, COND=256, D_FF=512, WS=8, SHIFT=4
// R4: GEMMs restructured for occupancy (128x64 tiles, acc 32 regs), LDS
//     XOR-swizzle (both-sides involution w/ global_load_lds), up-gate GEMM
//     redesigned (was 48KB LDS + 300 regs -> 11% occupancy, 156us).
// ---------------------------------------------------------------------------

using short8 = __attribute__((ext_vector_type(8))) short;
using f32x4  = __attribute__((ext_vector_type(4))) float;

#define DEVINL __device__ __forceinline__

DEVINL float bf2f(unsigned short u) {
    union { unsigned u; float f; } v; v.u = ((unsigned)u) << 16; return v.f;
}
DEVINL unsigned short f2bf(float f) { // round-to-nearest-even
    union { float f; unsigned u; } v; v.f = f;
    unsigned u = v.u;
    return (unsigned short)((u + 0x7FFFu + ((u >> 16) & 1u)) >> 16);
}
DEVINL void unpack8(uint4 pk, float* f) {
    unsigned w[4] = { pk.x, pk.y, pk.z, pk.w };
#pragma unroll
    for (int t = 0; t < 4; ++t) {
        union { unsigned u; float f; } lo, hi;
        lo.u = w[t] << 16; hi.u = w[t] & 0xffff0000u;
        f[2 * t] = lo.f; f[2 * t + 1] = hi.f;
    }
}
// async global->LDS, 16B per lane; LDS dest is wave-uniform base + lane*16
DEVINL void gload_lds16(const void* g, void* l) {
    __builtin_amdgcn_global_load_lds(
        (__attribute__((address_space(1))) void*)(unsigned long long)(uintptr_t)g,
        (__attribute__((address_space(3))) void*)(unsigned)(uintptr_t)l,
        16, 0, 0);
}
// swizzled LDS byte offset for row-major [rows][64 bf16] tile (128B rows).
// Content at (row, kb) holds global k-byte kb ^ ((row&7)<<4); source lanes
// pre-swizzled with skel = ((lane&7)^(lane>>3))*8 so stage∘read = identity.
DEVINL int swz(int row, int kb) { return row * 128 + (kb ^ ((row & 7) << 4)); }

// ---------------------------------------------------------------------------
// 1) convert all four weight matrices to bf16 into ws
__global__ __launch_bounds__(256)
void wconv_kernel(const float* __restrict__ qkvw, const float* __restrict__ outw,
                  const float* __restrict__ upw, const float* __restrict__ downw,
                  unsigned short* __restrict__ dst)
{
    const int i = blockIdx.x * 256 + threadIdx.x; // grid exactly 655360/256
    float v;
    if (i < 196608)      v = qkvw[i];
    else if (i < 262144) v = outw[i - 196608];
    else if (i < 524288) v = upw[i - 262144];
    else                 v = downw[i - 524288];
    dst[i] = f2bf(v);
}

// ---------------------------------------------------------------------------
// 2) s{1,2}[b][c] = dot(cond[b], norm_w[c]) + 1
__global__ __launch_bounds__(256)
void scales_kernel(const float* __restrict__ cond, const float* __restrict__ n1w,
                   const float* __restrict__ n2w, float* __restrict__ s1, float* __restrict__ s2)
{
    const int b = blockIdx.x & 3, which = blockIdx.x >> 2;
    const int c = threadIdx.x;
    const float* wrow = (which ? n2w : n1w) + (size_t)c * 256;
    const float* cb = cond + (size_t)b * 256;
    float acc = 0.f;
    for (int j = 0; j < 256; ++j) acc += cb[j] * wrow[j];
    (which ? s2 : s1)[b * 256 + c] = acc + 1.0f;
}

// ---------------------------------------------------------------------------
// 3) RMSNorm: one wave per token (256 ch), out bf16
__global__ __launch_bounds__(256)
void rmsnorm_kernel(const float* __restrict__ x, const float* __restrict__ s,
                    unsigned short* __restrict__ out)
{
    const int t = blockIdx.x * 4 + (threadIdx.x >> 6);
    const int lane = threadIdx.x & 63;
    const float4 xv = *(const float4*)(x + (size_t)t * 256 + lane * 4);
    float ss = xv.x * xv.x + xv.y * xv.y + xv.z * xv.z + xv.w * xv.w;
#pragma unroll
    for (int off = 32; off; off >>= 1) ss += __shfl_xor(ss, off);
    const float rstd = rsqrtf(ss * (1.f / 256.f) + 1e-6f);
    const int b = t >> 14;
    const float4 sv = *(const float4*)(s + b * 256 + lane * 4);
    unsigned short o[4] = { f2bf(xv.x * sv.x * rstd), f2bf(xv.y * sv.y * rstd),
                            f2bf(xv.z * sv.z * rstd), f2bf(xv.w * sv.w * rstd) };
    *(uint2*)(out + (size_t)t * 256 + lane * 4) = *(uint2*)o;
}

// ---------------------------------------------------------------------------
// 4) GEMM  C[M,N] = A[M,K] @ Bw[N,K]^T   (bf16 in, fp32 acc)
//    Tile 128Mx64N, 4 waves (2x2 of 64x32), acc[4][2]=32 regs/lane, LDS 24KB,
//    target 4 waves/SIMD via __launch_bounds__(256,4). Swizzled LDS.
//    EPI 0: bf16 out | 1: fp32 out = resid + acc
template<int EPI>
__global__ __launch_bounds__(256, 4)
void gemm_bt(const unsigned short* __restrict__ A, const unsigned short* __restrict__ Bw,
             const float* __restrict__ resid, void* __restrict__ outp,
             int M, int N, int K)
{
    __shared__ char smem[24576]; // A[128][64] 16K | B[64][64] 8K
    const int tid = threadIdx.x;
    const int wave = tid >> 6, lane = tid & 63;
    const int n0 = blockIdx.x * 64;
    const int m0 = blockIdx.y * 128;
    const int wm = wave >> 1, wn = wave & 1;

    f32x4 acc[4][2] = {};

    const int lrow8 = lane >> 3;                  // row within 8-row chunk
    const int skel = ((lane & 7) ^ lrow8) * 8;    // pre-swizzled source k-elem

    for (int k0 = 0; k0 < K; k0 += 64) {
        __syncthreads();
#pragma unroll
        for (int i = 0; i < 6; ++i) {
            const int cc = wave * 6 + i;          // 24 chunks of 1024B (8 rows)
            const unsigned short* src;
            if (cc < 16) src = A  + (size_t)(m0 + cc * 8 + lrow8) * K + k0 + skel;
            else         src = Bw + (size_t)(n0 + (cc - 16) * 8 + lrow8) * K + k0 + skel;
            gload_lds16(src, smem + cc * 1024);
        }
        __syncthreads();
#pragma unroll
        for (int kk = 0; kk < 2; ++kk) {
            const int kb = kk * 64 + (lane >> 4) * 16; // byte offset in 128B row
            short8 a[4], b[2];
#pragma unroll
            for (int m = 0; m < 4; ++m)
                a[m] = *(const short8*)(smem + swz(wm * 64 + m * 16 + (lane & 15), kb));
#pragma unroll
            for (int n = 0; n < 2; ++n)
                b[n] = *(const short8*)(smem + 16384 + swz(wn * 32 + n * 16 + (lane & 15), kb));
#pragma unroll
            for (int m = 0; m < 4; ++m)
#pragma unroll
                for (int n = 0; n < 2; ++n)
                    acc[m][n] = __builtin_amdgcn_mfma_f32_16x16x32_bf16(a[m], b[n], acc[m][n], 0, 0, 0);
        }
    }
    // epilogue: C row = (lane>>4)*4 + j, col = lane&15 (m89-verified layout)
    const int rb = m0 + wm * 64 + ((lane >> 4) << 2);
    const int cb = n0 + wn * 32 + (lane & 15);
#pragma unroll
    for (int m = 0; m < 4; ++m)
#pragma unroll
        for (int n = 0; n < 2; ++n)
#pragma unroll
            for (int j = 0; j < 4; ++j) {
                const int row = rb + m * 16 + j;
                const int col = cb + n * 16;
                const size_t idx = (size_t)row * N + col;
                if constexpr (EPI == 0)
                    ((unsigned short*)outp)[idx] = f2bf(acc[m][n][j]);
                else
                    ((float*)outp)[idx] = resid[idx] + acc[m][n][j];
            }
}

// ---------------------------------------------------------------------------
// 4b) fused up-GEMM + GELU gate: HG[M,512] = (XN2@Wup_a^T) * gelu(XN2@Wup_g^T)
//     Tile 128Mx64hcols, dual acc (a+g) = 64 regs/lane, LDS 32KB.
__global__ __launch_bounds__(256, 2)
void gemm_upgate(const unsigned short* __restrict__ A, const unsigned short* __restrict__ Bw,
                 unsigned short* __restrict__ outp)
{
    __shared__ char smem[32768]; // A[128][64] 16K | Ba[64][64] 8K | Bg[64][64] 8K
    const int K = 256;
    const int tid = threadIdx.x;
    const int wave = tid >> 6, lane = tid & 63;
    const int n0 = blockIdx.x * 64;
    const int m0 = blockIdx.y * 128;
    const int wm = wave >> 1, wn = wave & 1;

    f32x4 acc[4][2] = {};
    f32x4 accg[4][2] = {};

    const int lrow8 = lane >> 3;
    const int skel = ((lane & 7) ^ lrow8) * 8;

    for (int k0 = 0; k0 < K; k0 += 64) {
        __syncthreads();
#pragma unroll
        for (int i = 0; i < 8; ++i) {
            const int cc = wave * 8 + i;          // 32 chunks
            const unsigned short* src;
            if (cc < 16)      src = A  + (size_t)(m0 + cc * 8 + lrow8) * K + k0 + skel;
            else if (cc < 24) src = Bw + (size_t)(n0 + (cc - 16) * 8 + lrow8) * K + k0 + skel;
            else              src = Bw + (size_t)(512 + n0 + (cc - 24) * 8 + lrow8) * K + k0 + skel;
            gload_lds16(src, smem + cc * 1024);
        }
        __syncthreads();
#pragma unroll
        for (int kk = 0; kk < 2; ++kk) {
            const int kb = kk * 64 + (lane >> 4) * 16;
            short8 a[4], b[2], bg[2];
#pragma unroll
            for (int m = 0; m < 4; ++m)
                a[m] = *(const short8*)(smem + swz(wm * 64 + m * 16 + (lane & 15), kb));
#pragma unroll
            for (int n = 0; n < 2; ++n) {
                const int r = wn * 32 + n * 16 + (lane & 15);
                b[n]  = *(const short8*)(smem + 16384 + swz(r, kb));
                bg[n] = *(const short8*)(smem + 24576 + swz(r, kb));
            }
#pragma unroll
            for (int m = 0; m < 4; ++m)
#pragma unroll
                for (int n = 0; n < 2; ++n) {
                    acc[m][n]  = __builtin_amdgcn_mfma_f32_16x16x32_bf16(a[m], b[n],  acc[m][n],  0, 0, 0);
                    accg[m][n] = __builtin_amdgcn_mfma_f32_16x16x32_bf16(a[m], bg[n], accg[m][n], 0, 0, 0);
                }
        }
    }
    const int rb = m0 + wm * 64 + ((lane >> 4) << 2);
    const int cb = n0 + wn * 32 + (lane & 15);
#pragma unroll
    for (int m = 0; m < 4; ++m)
#pragma unroll
        for (int n = 0; n < 2; ++n)
#pragma unroll
            for (int j = 0; j < 4; ++j) {
                const int row = rb + m * 16 + j;
                const int col = cb + n * 16;
                const float g = accg[m][n][j];
                const float h = acc[m][n][j] * (0.5f * g * (1.0f + erff(g * 0.70710678118654752f)));
                outp[(size_t)row * 512 + col] = f2bf(h);
            }
}

// ---------------------------------------------------------------------------
// 5) q/k L2-norm (*sqrt(10)) + RoPE + shifted-window scatter. One wave per (token, head).
__global__ __launch_bounds__(256)
void windowrope_kernel(const unsigned short* __restrict__ qkv, const float* __restrict__ pos,
                       const float* __restrict__ freqs, const float* __restrict__ sattn,
                       unsigned short* __restrict__ qw, unsigned short* __restrict__ kw,
                       unsigned short* __restrict__ vw)
{
    const int gid = blockIdx.x * 4 + (threadIdx.x >> 6);
    const int lane = threadIdx.x & 63;      // d
    const int t = gid >> 2, n = gid & 3;
    const int b = t >> 14;
    const int h = (t >> 7) & 127, w = t & 127;

    const size_t base = (size_t)t * 768 + n * 64 + lane;
    float q = bf2f(qkv[base]);
    float k = bf2f(qkv[base + 256]);
    const float v = bf2f(qkv[base + 512]);

    float sq = q * q, sk = k * k;
#pragma unroll
    for (int off = 32; off; off >>= 1) { sq += __shfl_xor(sq, off); sk += __shfl_xor(sk, off); }
    const float sc = sqrtf(sattn[n]);
    q *= sc * rsqrtf(sq + 1e-6f);   // sum (not mean) + eps, per reference
    k *= sc * rsqrtf(sk + 1e-6f);

    const float qo = __shfl_xor(q, 16);   // rope partner (d ^ 16)
    const float ko = __shfl_xor(k, 16);
    if (lane < 32) {
        const int i = lane & 15;
        const float p = pos[(size_t)t * 2 + (i >> 3)];
        const float th = p * freqs[n * 8 + (i & 7)];
        float sth, cth;
        sincosf(th, &sth, &cth);
        if (lane < 16) { q = q * cth - qo * sth; k = k * cth - ko * sth; }
        else           { q = q * cth + qo * sth; k = k * cth + ko * sth; }
    }

    const int hr = (h + 4) & 127, wr = (w + 4) & 127;
    const int wh = hr >> 3, ww = wr >> 3;
    const int qp = (hr & 7) * 8 + (wr & 7);
    const size_t wbase = ((size_t)((b * 4 + n) * 256 + wh * 16 + ww) * 64 + qp) * 64 + lane;
    qw[wbase] = f2bf(q);
    kw[wbase] = f2bf(k);
    vw[wbase] = f2bf(v);
}

// ---------------------------------------------------------------------------
// 6) per-window attention. 1 wave per window (64 queries, lane = query row).
__global__ __launch_bounds__(64, 1)
void attn_kernel(const unsigned short* __restrict__ qw, const unsigned short* __restrict__ kw,
                 const unsigned short* __restrict__ vw, unsigned short* __restrict__ otok)
{
    __shared__ unsigned short Ks[4096];
    __shared__ unsigned short Vs[4096];
    const int bid = blockIdx.x;                  // ((b*4+n)*16+wh)*16+ww
    const int lane = threadIdx.x;
    const size_t wbase = (size_t)bid * 4096;

#pragma unroll
    for (int i = 0; i < 8; ++i) {
        const int idx = (i * 64 + lane) * 8;
        *(uint4*)(Ks + idx) = *(const uint4*)(kw + wbase + idx);
        *(uint4*)(Vs + idx) = *(const uint4*)(vw + wbase + idx);
    }
    float q[64];
#pragma unroll
    for (int i = 0; i < 8; ++i) {
        const uint4 pk = *(const uint4*)(qw + wbase + (size_t)lane * 64 + i * 8);
        unpack8(pk, q + i * 8);
    }
    __syncthreads();

    const int wh = (bid >> 4) & 15, ww = bid & 15;
    unsigned long long mask = ~0ull;
    if (wh == 0) mask &= (lane < 32) ? 0x00000000FFFFFFFFull : 0xFFFFFFFF00000000ull;
    if (ww == 0) mask &= ((lane & 7) < 4) ? 0x0F0F0F0F0F0F0F0Full : 0xF0F0F0F0F0F0F0F0ull;

    float o[64];
#pragma unroll
    for (int d = 0; d < 64; ++d) o[d] = 0.f;
    float sum = 0.f;

    for (int j = 0; j < 64; ++j) {
        float part[8];
#pragma unroll
        for (int dv = 0; dv < 8; ++dv) {
            const uint4 pk = *(const uint4*)(Ks + j * 64 + dv * 8);
            float f[8]; unpack8(pk, f);
            float a = 0.f;
#pragma unroll
            for (int u = 0; u < 8; ++u) a = fmaf(q[dv * 8 + u], f[u], a);
            part[dv] = a;
        }
        float s = ((part[0] + part[1]) + (part[2] + part[3])) +
                  ((part[4] + part[5]) + (part[6] + part[7]));
        float p = ((mask >> j) & 1ull) ? __expf(s - 10.f) : 0.f;
        sum += p;
#pragma unroll
        for (int dv = 0; dv < 8; ++dv) {
            const uint4 pk = *(const uint4*)(Vs + j * 64 + dv * 8);
            float f[8]; unpack8(pk, f);
#pragma unroll
            for (int u = 0; u < 8; ++u) o[dv * 8 + u] = fmaf(p, f[u], o[dv * 8 + u]);
        }
    }
    const float inv = 1.f / sum;

    const int b = bid >> 10, n = (bid >> 8) & 3;
    const int h = (wh * 8 + (lane >> 3) - 4) & 127;
    const int w = (ww * 8 + (lane & 7) - 4) & 127;
    unsigned short* dst = otok + ((size_t)(b * 128 + h) * 128 + w) * 256 + n * 64;
#pragma unroll
    for (int i = 0; i < 8; ++i) {
        unsigned short tmp[8];
#pragma unroll
        for (int u = 0; u < 8; ++u) tmp[u] = f2bf(o[i * 8 + u] * inv);
        *(uint4*)(dst + i * 8) = *(uint4*)tmp;
    }
}

// ---------------------------------------------------------------------------
extern "C" void kernel_launch(void* const* d_in, const int* in_sizes, int n_in,
                              void* d_out, int out_size, void* d_ws, size_t ws_size,
                              hipStream_t stream)
{
    (void)in_sizes; (void)n_in; (void)out_size; (void)ws_size;
    const float* x     = (const float*)d_in[0];
    const float* pos   = (const float*)d_in[1];
    const float* cond  = (const float*)d_in[2];
    const float* n1w   = (const float*)d_in[3];
    const float* qkvw  = (const float*)d_in[4];
    const float* sattn = (const float*)d_in[5];
    const float* freqs = (const float*)d_in[6];
    const float* outw  = (const float*)d_in[7];
    const float* n2w   = (const float*)d_in[8];
    const float* upw   = (const float*)d_in[9];
    const float* downw = (const float*)d_in[10];

    // workspace layout (bytes), regions time-aliased; peak ~203.5 MB
    char* ws = (char*)d_ws;
    unsigned short* WB    = (unsigned short*)(ws);
    unsigned short* Wqkv  = WB;
    unsigned short* Wout  = WB + 196608;
    unsigned short* Wup   = WB + 262144;
    unsigned short* Wdown = WB + 524288;
    float* S1 = (float*)(ws + 1310720);
    float* S2 = (float*)(ws + 1314816);
    unsigned short* XN   = (unsigned short*)(ws + 2097152);   // t1-t2
    unsigned short* QW   = (unsigned short*)(ws + 2097152);   // t3-t4 (XN dead)
    unsigned short* KW   = (unsigned short*)(ws + 35651584);
    unsigned short* VW   = (unsigned short*)(ws + 69206016);
    unsigned short* QKV  = (unsigned short*)(ws + 102760448); // t2-t3
    unsigned short* OTOK = (unsigned short*)(ws + 102760448); // t4-t5 (QKV dead)
    float*          X1   = (float*)(ws + 136314880);          // t5-end
    unsigned short* XN2  = (unsigned short*)(ws + 2097152);   // t6-t7 (QW dead)
    unsigned short* HG   = (unsigned short*)(ws + 35651584);  // t7-t9 (KW/VW dead)

    wconv_kernel<<<2560, 256, 0, stream>>>(qkvw, outw, upw, downw, WB);
    scales_kernel<<<8, 256, 0, stream>>>(cond, n1w, n2w, S1, S2);
    rmsnorm_kernel<<<16384, 256, 0, stream>>>(x, S1, XN);
    gemm_bt<0><<<dim3(12, 512), 256, 0, stream>>>(XN, Wqkv, nullptr, QKV, 65536, 768, 256);
    windowrope_kernel<<<65536, 256, 0, stream>>>(QKV, pos, freqs, sattn, QW, KW, VW);
    attn_kernel<<<4096, 64, 0, stream>>>(QW, KW, VW, OTOK);
    gemm_bt<1><<<dim3(4, 512), 256, 0, stream>>>(OTOK, Wout, x, X1, 65536, 256, 256);
    rmsnorm_kernel<<<16384, 256, 0, stream>>>(X1, S2, XN2);
    gemm_upgate<<<dim3(8, 512), 256, 0, stream>>>(XN2, Wup, HG);
    gemm_bt<1><<<dim3(4, 512), 256, 0, stream>>>(HG, Wdown, X1, (float*)d_out, 65536, 256, 512);
}